// Round 4
// baseline (10.033 us; speedup 1.0000x reference)
//
#include <hip/hip_runtime.h>
#include <math.h>

// Analytic reduction of the "quantum" feature map:
//   product state + CRX(0)=identity  =>  <Z_q> = cos(a_q) * cos(b_q)
//   => qf[q] = cos(x0)cos(x1) (even q) or cos(x3)cos(x4) (odd q).
// Then: out = tanh([x, qf] @ W1 + b1) @ W2 + b2.
//
// Layout: lane = sample (64 samples per block), 16 waves per block, wave w
// owns hidden units [16w, 16w+16). Loop nest is k-outer / unit-inner so the
// 16 weights needed per k are CONSECUTIVE wave-uniform floats ->
// one s_load_dwordx16 per k (18 wide scalar loads per wave total), and the
// FMA stream is 16 independent accumulator chains (full ILP). No LDS in the
// hot loop.

constexpr int DIN = 6;
constexpr int NQ = 10;
constexpr int K = DIN + NQ;        // 16
constexpr int H = 256;
constexpr int WAVES = 16;
constexpr int TPB = WAVES * 64;    // 1024 threads
constexpr int SPB = 64;            // samples per block (one per lane)
constexpr int HPW = H / WAVES;     // 16 hidden units per wave

__global__ __launch_bounds__(TPB) void qnn_fused_kernel(
    const float* __restrict__ x,    // [B, 6]
    const float* __restrict__ W1,   // [16, 256]
    const float* __restrict__ b1,   // [256]
    const float* __restrict__ W2,   // [256]
    const float* __restrict__ b2,   // [1]
    float* __restrict__ out,        // [B]
    int B)
{
    __shared__ float partial[WAVES][SPB];   // 4 KB

    const int lane = threadIdx.x & 63;
    const int wid  = __builtin_amdgcn_readfirstlane(threadIdx.x >> 6);
    const int sample = blockIdx.x * SPB + lane;

    // Per-lane features (24-byte rows are float2-aligned).
    float c[K];
    if (sample < B) {
        const float2* xp = (const float2*)(x + sample * DIN);
        const float2 a0 = xp[0], a1 = xp[1], a2 = xp[2];
        c[0] = a0.x; c[1] = a0.y; c[2] = a1.x;
        c[3] = a1.y; c[4] = a2.x; c[5] = a2.y;
    } else {
#pragma unroll
        for (int k = 0; k < DIN; ++k) c[k] = 0.0f;
    }
    const float u = __cosf(c[0]) * __cosf(c[1]);
    const float v = __cosf(c[3]) * __cosf(c[4]);
#pragma unroll
    for (int q = 0; q < NQ; q += 2) { c[DIN + q] = u; c[DIN + q + 1] = v; }

    const int hh0 = wid * HPW;      // wave-uniform (SGPR)

    // 16 independent accumulators, init from one b1 dwordx16.
    float s[HPW];
    {
        const float* bp = b1 + hh0;
#pragma unroll
        for (int i = 0; i < HPW; ++i) s[i] = bp[i];
    }

    // k-outer: one s_load_dwordx16 of consecutive W1 per k, 16 indep FMAs.
#pragma unroll
    for (int k = 0; k < K; ++k) {
        const float* wrow = W1 + k * H + hh0;
#pragma unroll
        for (int i = 0; i < HPW; ++i)
            s[i] = fmaf(c[k], wrow[i], s[i]);
    }

    // tanh + W2 dot (W2 slice is one more dwordx16).
    float acc = 0.0f;
    {
        const float* w2p = W2 + hh0;
#pragma unroll
        for (int i = 0; i < HPW; ++i) {
            const float e = __expf(2.0f * s[i]);
            const float t = 1.0f - 2.0f * __builtin_amdgcn_rcpf(e + 1.0f);
            acc = fmaf(t, w2p[i], acc);
        }
    }

    partial[wid][lane] = acc;
    __syncthreads();

    if (wid == 0) {
        float r = b2[0];
#pragma unroll
        for (int j = 0; j < WAVES; ++j) r += partial[j][lane];
        if (sample < B) out[sample] = r;   // coalesced 256B store per wave
    }
}

extern "C" void kernel_launch(void* const* d_in, const int* in_sizes, int n_in,
                              void* d_out, int out_size, void* d_ws, size_t ws_size,
                              hipStream_t stream) {
    const float* x  = (const float*)d_in[0];
    const float* W1 = (const float*)d_in[1];
    const float* b1 = (const float*)d_in[2];
    const float* W2 = (const float*)d_in[3];
    const float* b2 = (const float*)d_in[4];
    float* out = (float*)d_out;

    const int B = in_sizes[0] / DIN;              // 16384
    const int blocks = (B + SPB - 1) / SPB;       // 256
    qnn_fused_kernel<<<blocks, TPB, 0, stream>>>(x, W1, b1, W2, b2, out, B);
}